// Round 6
// baseline (114.931 us; speedup 1.0000x reference)
//
#include <hip/hip_runtime.h>
#include <hip/hip_bf16.h>

// QKVAttentionLegacy: qkv (4,3072,1024) fp32, 16 heads, ch=64.
// R6: LDS-throughput attack #2. Wave owns 64 t (4 n-tiles): each kf/vf
// ds_read_b128 feeds 4 MFMAs. K staged via in-register 4x4 transpose ->
// ds_write_b64 with XOR-even chunk swizzle (write ~bank-floor, read exactly
// at b128 floor). S^T orientation, P in wave-private dead-Q rows (b64 writes),
// per-lane denominator, direct coalesced O^T stores. BM=256, grid 256
// (bh-fastest, 1 blk/CU), single-buffer + register prefetch.

typedef __bf16 bf16_8 __attribute__((ext_vector_type(8)));
typedef __bf16 bf16_4 __attribute__((ext_vector_type(4)));
typedef float floatx4 __attribute__((ext_vector_type(4)));

#define NTHREADS 256
#define STRIDE 72            // bf16 elems per LDS row (144 B)
#define NSTEPS 16

#if __has_builtin(__builtin_amdgcn_exp2f)
#define EXP2(x) __builtin_amdgcn_exp2f(x)
#else
#define EXP2(x) exp2f(x)
#endif
// (1/8)*log2(e): qk scale + exp->exp2, folded into Q staging (one bf16 rounding).
#define QSCALE 0.18033688011112042f

// LDS: q_s [256][72]bf16 @0 (36864; rows [64w,64w+64) = wave w's P scratch)
//      k_s [64][72] @36864 (K^T [s][c], chunk-swizzled) | v_s [64][72] @46080
#define LDS_BYTES 55296

__global__ __launch_bounds__(NTHREADS, 2)
void attn_kernel(const float* __restrict__ qkv, float* __restrict__ out) {
    __shared__ char smem[LDS_BYTES];
    __bf16* q_s = (__bf16*)smem;
    __bf16* k_s = (__bf16*)(smem + 36864);
    __bf16* v_s = (__bf16*)(smem + 46080);

    const int tid  = threadIdx.x;
    const int wave = tid >> 6;
    const int lane = tid & 63;
    const int quad = lane >> 4;
    const int i16  = lane & 15;

    const int bx = blockIdx.x;           // 256 = 4 t-chunks * 64 bh (bh fastest)
    const int bh = bx & 63;
    const int t0 = (bx >> 6) << 8;       // *256

    const float* qg = qkv + (size_t)bh * 196608;
    const float* kg = qg + 65536;
    const float* vg = qg + 131072;

    // staging thread coords: i = tid&15 (s/t group), G = tid>>4 (c-chunk 4G)
    const int si = tid & 15;
    const int sG = tid >> 4;
    const int c0 = sG << 2;

    // ---- prologue: Q [256t][64c], scaled + transposed + chunk-swizzled ----
    #pragma unroll
    for (int tj = 0; tj < 4; ++tj) {
        float4 q4[4];
        #pragma unroll
        for (int jj = 0; jj < 4; ++jj)
            q4[jj] = *(const float4*)(qg + (c0 + jj) * 1024 + t0 + tj * 64 + si * 4);
        #pragma unroll
        for (int rr = 0; rr < 4; ++rr) {
            int trow = tj * 64 + si * 4 + rr;
            bf16_4 w;
            w[0] = (__bf16)(((const float*)&q4[0])[rr] * QSCALE);
            w[1] = (__bf16)(((const float*)&q4[1])[rr] * QSCALE);
            w[2] = (__bf16)(((const float*)&q4[2])[rr] * QSCALE);
            w[3] = (__bf16)(((const float*)&q4[3])[rr] * QSCALE);
            *(bf16_4*)&q_s[trow * STRIDE + ((sG ^ (trow & 14)) << 2)] = w;
        }
    }
    // ---- K/V tile 0 (K: reg-transpose + swizzled b64; V: natural b64) ----
    {
        float4 k4[4], v4[4];
        #pragma unroll
        for (int jj = 0; jj < 4; ++jj) {
            k4[jj] = *(const float4*)(kg + (c0 + jj) * 1024 + si * 4);
            v4[jj] = *(const float4*)(vg + (c0 + jj) * 1024 + si * 4);
        }
        #pragma unroll
        for (int rr = 0; rr < 4; ++rr) {
            int srow = si * 4 + rr;
            bf16_4 w;
            w[0] = (__bf16)((const float*)&k4[0])[rr];
            w[1] = (__bf16)((const float*)&k4[1])[rr];
            w[2] = (__bf16)((const float*)&k4[2])[rr];
            w[3] = (__bf16)((const float*)&k4[3])[rr];
            *(bf16_4*)&k_s[srow * STRIDE + ((sG ^ (srow & 14)) << 2)] = w;
        }
        #pragma unroll
        for (int jj = 0; jj < 4; ++jj) {
            bf16_4 w;
            w[0] = (__bf16)v4[jj].x; w[1] = (__bf16)v4[jj].y;
            w[2] = (__bf16)v4[jj].z; w[3] = (__bf16)v4[jj].w;
            *(bf16_4*)&v_s[(c0 + jj) * STRIDE + si * 4] = w;
        }
    }
    __syncthreads();

    // Q B-frags for this wave's four 16-t tiles, in regs all loop
    bf16_8 qf[4][2];
    #pragma unroll
    for (int tt = 0; tt < 4; ++tt) {
        int row = wave * 64 + tt * 16 + i16;
        int e2 = (row >> 1) & 7;
        #pragma unroll
        for (int kk = 0; kk < 2; ++kk)
            qf[tt][kk] = *(const bf16_8*)&q_s[row * STRIDE + (((kk * 4 + quad) ^ e2) << 3)];
    }

    floatx4 O[4][4];                     // [tt][cn] O^T: row c=cn*16+4q+r, col t
    #pragma unroll
    for (int tt = 0; tt < 4; ++tt)
        #pragma unroll
        for (int cn = 0; cn < 4; ++cn) O[tt][cn] = (floatx4){0.f, 0.f, 0.f, 0.f};
    float l[4] = {0.f, 0.f, 0.f, 0.f};

    __bf16* pw = q_s + (size_t)(wave * 64) * STRIDE;  // wave-private P [64t][64s]

    for (int is = 0; is < NSTEPS; ++is) {
        float4 kr[4], vr[4];
        if (is < NSTEPS - 1) {
            const int s0n = (is + 1) * 64;
            #pragma unroll
            for (int jj = 0; jj < 4; ++jj) {
                kr[jj] = *(const float4*)(kg + (c0 + jj) * 1024 + s0n + si * 4);
                vr[jj] = *(const float4*)(vg + (c0 + jj) * 1024 + s0n + si * 4);
            }
        }

        // ---- S^T = K (Qs)^T : each kf read feeds 4 t-tiles ----
        floatx4 St[4][4];                // [tt][sb]
        #pragma unroll
        for (int sb = 0; sb < 4; ++sb) {
            int srow = sb * 16 + i16;
            int e2 = (srow >> 1) & 7;
            bf16_8 kf0 = *(const bf16_8*)&k_s[srow * STRIDE + ((quad ^ e2) << 3)];
            bf16_8 kf1 = *(const bf16_8*)&k_s[srow * STRIDE + (((4 + quad) ^ e2) << 3)];
            #pragma unroll
            for (int tt = 0; tt < 4; ++tt) {
                floatx4 acc = __builtin_amdgcn_mfma_f32_16x16x32_bf16(
                    kf0, qf[tt][0], (floatx4){0.f, 0.f, 0.f, 0.f}, 0, 0, 0);
                St[tt][sb] = __builtin_amdgcn_mfma_f32_16x16x32_bf16(
                    kf1, qf[tt][1], acc, 0, 0, 0);
            }
        }
        // ---- P = exp2(S^T); pack 4 contiguous s -> ds_write_b64 ----
        // lane (q,i16) reg r of St[tt][sb] = P^T[s=sb*16+4q+r][t=tt*16+i16]
        #pragma unroll
        for (int tt = 0; tt < 4; ++tt)
            #pragma unroll
            for (int sb = 0; sb < 4; ++sb) {
                float p0 = EXP2(St[tt][sb][0]);
                float p1 = EXP2(St[tt][sb][1]);
                float p2 = EXP2(St[tt][sb][2]);
                float p3 = EXP2(St[tt][sb][3]);
                l[tt] += (p0 + p1) + (p2 + p3);
                bf16_4 pk;
                pk[0] = (__bf16)p0; pk[1] = (__bf16)p1;
                pk[2] = (__bf16)p2; pk[3] = (__bf16)p3;
                *(bf16_4*)&pw[(tt * 16 + i16) * STRIDE + sb * 16 + quad * 4] = pk;
            }
        // ---- af (wave-private region, intra-wave DS ordering, no barrier) ----
        bf16_8 af[4][2];
        #pragma unroll
        for (int tt = 0; tt < 4; ++tt)
            #pragma unroll
            for (int kk = 0; kk < 2; ++kk)
                af[tt][kk] = *(const bf16_8*)&pw[(tt * 16 + i16) * STRIDE + kk * 32 + quad * 8];
        // ---- O^T += V P^T : each vf read feeds 4 t-tiles ----
        #pragma unroll
        for (int cn = 0; cn < 4; ++cn)
            #pragma unroll
            for (int kk = 0; kk < 2; ++kk) {
                bf16_8 vf = *(const bf16_8*)&v_s[(cn * 16 + i16) * STRIDE + kk * 32 + quad * 8];
                #pragma unroll
                for (int tt = 0; tt < 4; ++tt)
                    O[tt][cn] = __builtin_amdgcn_mfma_f32_16x16x32_bf16(
                        vf, af[tt][kk], O[tt][cn], 0, 0, 0);
            }

        if (is < NSTEPS - 1) {
            __syncthreads();             // all waves done reading k_s/v_s
            #pragma unroll
            for (int rr = 0; rr < 4; ++rr) {
                int srow = si * 4 + rr;
                bf16_4 w;
                w[0] = (__bf16)((const float*)&kr[0])[rr];
                w[1] = (__bf16)((const float*)&kr[1])[rr];
                w[2] = (__bf16)((const float*)&kr[2])[rr];
                w[3] = (__bf16)((const float*)&kr[3])[rr];
                *(bf16_4*)&k_s[srow * STRIDE + ((sG ^ (srow & 14)) << 2)] = w;
            }
            #pragma unroll
            for (int jj = 0; jj < 4; ++jj) {
                bf16_4 w;
                w[0] = (__bf16)vr[jj].x; w[1] = (__bf16)vr[jj].y;
                w[2] = (__bf16)vr[jj].z; w[3] = (__bf16)vr[jj].w;
                *(bf16_4*)&v_s[(c0 + jj) * STRIDE + si * 4] = w;
            }
            __syncthreads();             // new tile visible
        }
    }

    // ---- denominators (sum 4 quads of column t) + direct O^T stores ----
    float* og = out + (size_t)bh * 65536 + t0 + wave * 64;
    #pragma unroll
    for (int tt = 0; tt < 4; ++tt) {
        float s = l[tt];
        s += __shfl_xor(s, 16);
        s += __shfl_xor(s, 32);
        const float linv = 1.0f / s;
        #pragma unroll
        for (int cn = 0; cn < 4; ++cn)
            #pragma unroll
            for (int r = 0; r < 4; ++r)
                og[(cn * 16 + 4 * quad + r) * 1024 + tt * 16 + i16] = O[tt][cn][r] * linv;
    }
}

extern "C" void kernel_launch(void* const* d_in, const int* in_sizes, int n_in,
                              void* d_out, int out_size, void* d_ws, size_t ws_size,
                              hipStream_t stream) {
    const float* qkv = (const float*)d_in[0];
    float* out = (float*)d_out;
    attn_kernel<<<dim3(256), dim3(NTHREADS), 0, stream>>>(qkv, out);
}

// Round 7
// 106.319 us; speedup vs baseline: 1.0810x; 1.0810x over previous
//
#include <hip/hip_runtime.h>
#include <hip/hip_bf16.h>

// QKVAttentionLegacy: qkv (4,3072,1024) fp32, 16 heads, ch=64.
// R7: R5 shape (BM=128, 4 waves x 32t, grid 512, 2 blk/CU) with:
//  - pad-free kappa-swizzled LDS (STRIDE 64): kappa(row)=((row>>1)+(row>>4))&7
//    applied at b64 granularity to K/Q/V/P. All staged writes at 4 dword/bank
//    (b64 floor), all frag reads at 8 dword/bank (b128 floor) - hand-verified.
//  - K/V double buffer, write-early: stage tile i+1 after compute of tile i,
//    ONE barrier/iter publishes next tile AND retires current reads.
//  - reg-transpose K staging (ds_write_b64, not 16x ds_write_b16).
// S^T orientation (mfma(kf,qf)), P in wave-private dead-Q rows, per-lane
// denominator, direct coalesced O^T stores (all R5/R6-verified).

typedef __bf16 bf16_8 __attribute__((ext_vector_type(8)));
typedef __bf16 bf16_4 __attribute__((ext_vector_type(4)));
typedef float floatx4 __attribute__((ext_vector_type(4)));

#define NTHREADS 256
#define STR 64               // bf16 elems per LDS row (128 B, no pad; swizzle only)
#define NSTEPS 16

#if __has_builtin(__builtin_amdgcn_exp2f)
#define EXP2(x) __builtin_amdgcn_exp2f(x)
#else
#define EXP2(x) exp2f(x)
#endif
// (1/8)*log2(e): qk scale + exp->exp2, folded into Q staging (one bf16 rounding).
#define QSCALE 0.18033688011112042f

// LDS: q_s [128][64]bf16 @0 (16384; rows [32w,32w+32) = wave w's P scratch)
//      k0 @16384 | k1 @24576 | v0 @32768 | v1 @40960  (each 64x64 = 8192 B)
#define LDS_BYTES 49152

__device__ __forceinline__ int kap(int row) { return ((row >> 1) + (row >> 4)) & 7; }

__global__ __launch_bounds__(NTHREADS, 2)
void attn_kernel(const float* __restrict__ qkv, float* __restrict__ out) {
    __shared__ char smem[LDS_BYTES];
    __bf16* q_s = (__bf16*)smem;
    __bf16* k0  = (__bf16*)(smem + 16384);
    __bf16* k1  = (__bf16*)(smem + 24576);
    __bf16* v0  = (__bf16*)(smem + 32768);
    __bf16* v1  = (__bf16*)(smem + 40960);

    const int tid  = threadIdx.x;
    const int wave = tid >> 6;
    const int lane = tid & 63;
    const int quad = lane >> 4;
    const int i16  = lane & 15;

    const int bx = blockIdx.x;           // 512 = 8 t-tiles * 64 bh (bh fastest -> XCD)
    const int bh = bx & 63;
    const int t0 = (bx >> 6) << 7;       // *128

    const float* qg = qkv + (size_t)bh * 196608;
    const float* kg = qg + 65536;
    const float* vg = qg + 131072;

    // staging thread coords: si = s/t-group (4 elems at si*4), sG = c-chunk
    const int si = tid & 15;
    const int sG = tid >> 4;             // 0..15 (b64 chunk = 4 c)
    const int c0 = sG << 2;

    // ---- prologue: Q [128t][64c] scaled+transposed+swizzled ----
    #pragma unroll
    for (int j = 0; j < 2; ++j) {
        int f  = j * NTHREADS + tid;     // 0..511
        int cG = f >> 5;                 // 0..15 (b64 chunk = 4 c)
        int ti = f & 31;                 // t-group: t = 4*ti
        float4 q4[4];
        #pragma unroll
        for (int jj = 0; jj < 4; ++jj)
            q4[jj] = *(const float4*)(qg + (cG * 4 + jj) * 1024 + t0 + ti * 4);
        #pragma unroll
        for (int rr = 0; rr < 4; ++rr) {
            int trow = ti * 4 + rr;
            bf16_4 w;
            w[0] = (__bf16)(((const float*)&q4[0])[rr] * QSCALE);
            w[1] = (__bf16)(((const float*)&q4[1])[rr] * QSCALE);
            w[2] = (__bf16)(((const float*)&q4[2])[rr] * QSCALE);
            w[3] = (__bf16)(((const float*)&q4[3])[rr] * QSCALE);
            *(bf16_4*)&q_s[trow * STR + ((cG ^ (kap(trow) << 1)) << 2)] = w;
        }
    }
    // ---- K/V tile 0 ----
    {
        float4 k4[4], v4[4];
        #pragma unroll
        for (int jj = 0; jj < 4; ++jj) {
            k4[jj] = *(const float4*)(kg + (c0 + jj) * 1024 + si * 4);
            v4[jj] = *(const float4*)(vg + (c0 + jj) * 1024 + si * 4);
        }
        #pragma unroll
        for (int rr = 0; rr < 4; ++rr) {
            int srow = si * 4 + rr;
            bf16_4 w;
            w[0] = (__bf16)((const float*)&k4[0])[rr];
            w[1] = (__bf16)((const float*)&k4[1])[rr];
            w[2] = (__bf16)((const float*)&k4[2])[rr];
            w[3] = (__bf16)((const float*)&k4[3])[rr];
            *(bf16_4*)&k0[srow * STR + ((sG ^ (kap(srow) << 1)) << 2)] = w;
        }
        #pragma unroll
        for (int jj = 0; jj < 4; ++jj) {
            int c = c0 + jj;
            bf16_4 w;
            w[0] = (__bf16)v4[jj].x; w[1] = (__bf16)v4[jj].y;
            w[2] = (__bf16)v4[jj].z; w[3] = (__bf16)v4[jj].w;
            *(bf16_4*)&v0[c * STR + ((si ^ (kap(c) << 1)) << 2)] = w;
        }
    }
    __syncthreads();

    // Q B-frags for this wave's two 16-t tiles (B[k=c][n=t]), in regs all loop
    bf16_8 qf[2][2];
    #pragma unroll
    for (int tt = 0; tt < 2; ++tt) {
        int row = wave * 32 + tt * 16 + i16;
        int x = kap(row);
        #pragma unroll
        for (int kk = 0; kk < 2; ++kk)
            qf[tt][kk] = *(const bf16_8*)&q_s[row * STR + ((((kk << 2) | quad) ^ x) << 3)];
    }

    floatx4 O[2][4];                     // [tt][cn] O^T: row c=cn*16+4q+r, col t
    #pragma unroll
    for (int tt = 0; tt < 2; ++tt)
        #pragma unroll
        for (int cn = 0; cn < 4; ++cn) O[tt][cn] = (floatx4){0.f, 0.f, 0.f, 0.f};
    float l[2] = {0.f, 0.f};

    __bf16* pw = q_s + (size_t)(wave * 32) * STR;   // wave-private P [32t][64s]
    const int xp0 = (i16 >> 1) & 7;      // kappa base for P rows (tt added per use)
    const int xv  = 0;                   // placeholder (computed per cn below)

    for (int is = 0; is < NSTEPS; ++is) {
        const __bf16* kc = (is & 1) ? k1 : k0;
        const __bf16* vc = (is & 1) ? v1 : v0;

        // issue global prefetch of tile is+1 (consumed at iter bottom)
        float4 kr[4], vr[4];
        if (is < NSTEPS - 1) {
            const int s0n = (is + 1) * 64;
            #pragma unroll
            for (int jj = 0; jj < 4; ++jj) {
                kr[jj] = *(const float4*)(kg + (c0 + jj) * 1024 + s0n + si * 4);
                vr[jj] = *(const float4*)(vg + (c0 + jj) * 1024 + s0n + si * 4);
            }
        }

        // ---- S^T = K (Qs)^T : each kf read feeds both t-tiles ----
        floatx4 St[2][4];
        #pragma unroll
        for (int sb = 0; sb < 4; ++sb) {
            int srow = sb * 16 + i16;
            int x = (sb + (i16 >> 1)) & 7;            // kap(srow)
            bf16_8 kf0 = *(const bf16_8*)&kc[srow * STR + ((quad ^ x) << 3)];
            bf16_8 kf1 = *(const bf16_8*)&kc[srow * STR + (((4 | quad) ^ x) << 3)];
            floatx4 a0 = (floatx4){0.f, 0.f, 0.f, 0.f};
            floatx4 a1 = (floatx4){0.f, 0.f, 0.f, 0.f};
            a0 = __builtin_amdgcn_mfma_f32_16x16x32_bf16(kf0, qf[0][0], a0, 0, 0, 0);
            a0 = __builtin_amdgcn_mfma_f32_16x16x32_bf16(kf1, qf[0][1], a0, 0, 0, 0);
            a1 = __builtin_amdgcn_mfma_f32_16x16x32_bf16(kf0, qf[1][0], a1, 0, 0, 0);
            a1 = __builtin_amdgcn_mfma_f32_16x16x32_bf16(kf1, qf[1][1], a1, 0, 0, 0);
            St[0][sb] = a0;
            St[1][sb] = a1;
        }
        // ---- P = exp2(S^T); pack 4 contiguous s -> swizzled ds_write_b64 ----
        #pragma unroll
        for (int tt = 0; tt < 2; ++tt) {
            int trow = tt * 16 + i16;
            int xp = (tt + xp0) & 7;                  // kap(trow) region-relative
            #pragma unroll
            for (int sb = 0; sb < 4; ++sb) {
                float p0 = EXP2(St[tt][sb][0]);
                float p1 = EXP2(St[tt][sb][1]);
                float p2 = EXP2(St[tt][sb][2]);
                float p3 = EXP2(St[tt][sb][3]);
                l[tt] += (p0 + p1) + (p2 + p3);
                bf16_4 pk;
                pk[0] = (__bf16)p0; pk[1] = (__bf16)p1;
                pk[2] = (__bf16)p2; pk[3] = (__bf16)p3;
                int ch = ((sb << 2) | quad) ^ (xp << 1);
                *(bf16_4*)&pw[trow * STR + (ch << 2)] = pk;
            }
        }
        // ---- af B-frags (wave-private region, intra-wave DS order, no barrier)
        bf16_8 af[2][2];
        #pragma unroll
        for (int tt = 0; tt < 2; ++tt) {
            int trow = tt * 16 + i16;
            int xp = (tt + xp0) & 7;
            #pragma unroll
            for (int kk = 0; kk < 2; ++kk)
                af[tt][kk] = *(const bf16_8*)&pw[trow * STR + ((((kk << 2) | quad) ^ xp) << 3)];
        }
        // ---- O^T += V P^T : each vf read feeds both t-tiles ----
        #pragma unroll
        for (int cn = 0; cn < 4; ++cn) {
            int crow = cn * 16 + i16;
            int xc = (cn + (i16 >> 1)) & 7;           // kap(crow)
            #pragma unroll
            for (int kk = 0; kk < 2; ++kk) {
                bf16_8 vf = *(const bf16_8*)&vc[crow * STR + ((((kk << 2) | quad) ^ xc) << 3)];
                O[0][cn] = __builtin_amdgcn_mfma_f32_16x16x32_bf16(vf, af[0][kk], O[0][cn], 0, 0, 0);
                O[1][cn] = __builtin_amdgcn_mfma_f32_16x16x32_bf16(vf, af[1][kk], O[1][cn], 0, 0, 0);
            }
        }

        // ---- write-early staging of tile is+1 into the alternate buffers ----
        if (is < NSTEPS - 1) {
            __bf16* kn = (is & 1) ? k0 : k1;
            __bf16* vn = (is & 1) ? v0 : v1;
            #pragma unroll
            for (int rr = 0; rr < 4; ++rr) {
                int srow = si * 4 + rr;
                bf16_4 w;
                w[0] = (__bf16)((const float*)&kr[0])[rr];
                w[1] = (__bf16)((const float*)&kr[1])[rr];
                w[2] = (__bf16)((const float*)&kr[2])[rr];
                w[3] = (__bf16)((const float*)&kr[3])[rr];
                *(bf16_4*)&kn[srow * STR + ((sG ^ (kap(srow) << 1)) << 2)] = w;
            }
            #pragma unroll
            for (int jj = 0; jj < 4; ++jj) {
                int c = c0 + jj;
                bf16_4 w;
                w[0] = (__bf16)vr[jj].x; w[1] = (__bf16)vr[jj].y;
                w[2] = (__bf16)vr[jj].z; w[3] = (__bf16)vr[jj].w;
                *(bf16_4*)&vn[c * STR + ((si ^ (kap(c) << 1)) << 2)] = w;
            }
        }
        // ONE barrier: publishes tile is+1 AND retires all reads of tile is
        __syncthreads();
    }

    // ---- denominators (sum 4 quads of column t) + direct O^T stores ----
    float* og = out + (size_t)bh * 65536 + t0 + wave * 32;
    #pragma unroll
    for (int tt = 0; tt < 2; ++tt) {
        float s = l[tt];
        s += __shfl_xor(s, 16);
        s += __shfl_xor(s, 32);
        const float linv = 1.0f / s;
        #pragma unroll
        for (int cn = 0; cn < 4; ++cn)
            #pragma unroll
            for (int r = 0; r < 4; ++r)
                og[(cn * 16 + 4 * quad + r) * 1024 + tt * 16 + i16] = O[tt][cn][r] * linv;
    }
}

extern "C" void kernel_launch(void* const* d_in, const int* in_sizes, int n_in,
                              void* d_out, int out_size, void* d_ws, size_t ws_size,
                              hipStream_t stream) {
    const float* qkv = (const float*)d_in[0];
    float* out = (float*)d_out;
    attn_kernel<<<dim3(512), dim3(NTHREADS), 0, stream>>>(qkv, out);
}

// Round 8
// 105.840 us; speedup vs baseline: 1.0859x; 1.0045x over previous
//
#include <hip/hip_runtime.h>
#include <hip/hip_bf16.h>

// QKVAttentionLegacy: qkv (4,3072,1024) fp32, 16 heads, ch=64.
// R8 = R7 + software-pipelined PV (one tile behind): iter i runs
// QK_i -> softmax_i -> PV_{i-1}, so PV's independent vf-reads/MFMAs fill the
// af-read + exp2 latency of softmax_i (and vice versa). V triple-buffered
// (tiles i-1, i, i+1 alive), K double-buffered, ONE barrier/iter (last skipped).
// All LDS swizzles identical to R7 (hand-verified bank floors).

typedef __bf16 bf16_8 __attribute__((ext_vector_type(8)));
typedef __bf16 bf16_4 __attribute__((ext_vector_type(4)));
typedef float floatx4 __attribute__((ext_vector_type(4)));

#define NTHREADS 256
#define STR 64               // bf16 elems per LDS row (128 B, swizzle not pad)
#define NSTEPS 16

#if __has_builtin(__builtin_amdgcn_exp2f)
#define EXP2(x) __builtin_amdgcn_exp2f(x)
#else
#define EXP2(x) exp2f(x)
#endif
// (1/8)*log2(e): qk scale + exp->exp2, folded into Q staging (one bf16 rounding).
#define QSCALE 0.18033688011112042f

// LDS: q_s [128][64]bf16 @0 (16384; rows [32w,32w+32) = wave w's P scratch)
//      k0 @16384 | k1 @24576 | v0 @32768 | v1 @40960 | v2 @49152 (each 8192)
#define LDS_BYTES 57344

__device__ __forceinline__ int kap(int row) { return ((row >> 1) + (row >> 4)) & 7; }

__global__ __launch_bounds__(NTHREADS, 2)
void attn_kernel(const float* __restrict__ qkv, float* __restrict__ out) {
    __shared__ char smem[LDS_BYTES];
    __bf16* q_s = (__bf16*)smem;
    __bf16* k0  = (__bf16*)(smem + 16384);
    __bf16* k1  = (__bf16*)(smem + 24576);
    __bf16* v0  = (__bf16*)(smem + 32768);
    __bf16* v1  = (__bf16*)(smem + 40960);
    __bf16* v2  = (__bf16*)(smem + 49152);

    const int tid  = threadIdx.x;
    const int wave = tid >> 6;
    const int lane = tid & 63;
    const int quad = lane >> 4;
    const int i16  = lane & 15;

    const int bx = blockIdx.x;           // 512 = 8 t-tiles * 64 bh (bh fastest -> XCD)
    const int bh = bx & 63;
    const int t0 = (bx >> 6) << 7;       // *128

    const float* qg = qkv + (size_t)bh * 196608;
    const float* kg = qg + 65536;
    const float* vg = qg + 131072;

    const int si = tid & 15;
    const int sG = tid >> 4;             // c-chunk (4 c per b64)
    const int c0 = sG << 2;

    // ---- prologue: Q [128t][64c] scaled+transposed+swizzled ----
    #pragma unroll
    for (int j = 0; j < 2; ++j) {
        int f  = j * NTHREADS + tid;
        int cG = f >> 5;
        int ti = f & 31;
        float4 q4[4];
        #pragma unroll
        for (int jj = 0; jj < 4; ++jj)
            q4[jj] = *(const float4*)(qg + (cG * 4 + jj) * 1024 + t0 + ti * 4);
        #pragma unroll
        for (int rr = 0; rr < 4; ++rr) {
            int trow = ti * 4 + rr;
            bf16_4 w;
            w[0] = (__bf16)(((const float*)&q4[0])[rr] * QSCALE);
            w[1] = (__bf16)(((const float*)&q4[1])[rr] * QSCALE);
            w[2] = (__bf16)(((const float*)&q4[2])[rr] * QSCALE);
            w[3] = (__bf16)(((const float*)&q4[3])[rr] * QSCALE);
            *(bf16_4*)&q_s[trow * STR + ((cG ^ (kap(trow) << 1)) << 2)] = w;
        }
    }
    // ---- K/V tile 0 ----
    {
        float4 k4[4], v4[4];
        #pragma unroll
        for (int jj = 0; jj < 4; ++jj) {
            k4[jj] = *(const float4*)(kg + (c0 + jj) * 1024 + si * 4);
            v4[jj] = *(const float4*)(vg + (c0 + jj) * 1024 + si * 4);
        }
        #pragma unroll
        for (int rr = 0; rr < 4; ++rr) {
            int srow = si * 4 + rr;
            bf16_4 w;
            w[0] = (__bf16)((const float*)&k4[0])[rr];
            w[1] = (__bf16)((const float*)&k4[1])[rr];
            w[2] = (__bf16)((const float*)&k4[2])[rr];
            w[3] = (__bf16)((const float*)&k4[3])[rr];
            *(bf16_4*)&k0[srow * STR + ((sG ^ (kap(srow) << 1)) << 2)] = w;
        }
        #pragma unroll
        for (int jj = 0; jj < 4; ++jj) {
            int c = c0 + jj;
            bf16_4 w;
            w[0] = (__bf16)v4[jj].x; w[1] = (__bf16)v4[jj].y;
            w[2] = (__bf16)v4[jj].z; w[3] = (__bf16)v4[jj].w;
            *(bf16_4*)&v0[c * STR + ((si ^ (kap(c) << 1)) << 2)] = w;
        }
    }
    __syncthreads();

    // Q B-frags for this wave's two 16-t tiles (B[k=c][n=t]), in regs all loop
    bf16_8 qf[2][2];
    #pragma unroll
    for (int tt = 0; tt < 2; ++tt) {
        int row = wave * 32 + tt * 16 + i16;
        int x = kap(row);
        #pragma unroll
        for (int kk = 0; kk < 2; ++kk)
            qf[tt][kk] = *(const bf16_8*)&q_s[row * STR + ((((kk << 2) | quad) ^ x) << 3)];
    }

    floatx4 O[2][4];
    #pragma unroll
    for (int tt = 0; tt < 2; ++tt)
        #pragma unroll
        for (int cn = 0; cn < 4; ++cn) O[tt][cn] = (floatx4){0.f, 0.f, 0.f, 0.f};
    float l[2] = {0.f, 0.f};

    __bf16* pw = q_s + (size_t)(wave * 32) * STR;   // wave-private P [32t][64s]
    const int xp0 = (i16 >> 1) & 7;

    bf16_8 afp[2][2];                    // af of tile is-1 (carried)
    int vprev = 2, vcur = 0, vnext = 1;  // V buffer rotation (tile % 3)

    for (int is = 0; is < NSTEPS; ++is) {
        const __bf16* kc = (is & 1) ? k1 : k0;

        // global prefetch of tile is+1
        float4 kr[4], vr[4];
        if (is < NSTEPS - 1) {
            const int s0n = (is + 1) * 64;
            #pragma unroll
            for (int jj = 0; jj < 4; ++jj) {
                kr[jj] = *(const float4*)(kg + (c0 + jj) * 1024 + s0n + si * 4);
                vr[jj] = *(const float4*)(vg + (c0 + jj) * 1024 + s0n + si * 4);
            }
        }

        // ---- S^T = K (Qs)^T ----
        floatx4 St[2][4];
        #pragma unroll
        for (int sb = 0; sb < 4; ++sb) {
            int srow = sb * 16 + i16;
            int x = (sb + (i16 >> 1)) & 7;            // kap(srow)
            bf16_8 kf0 = *(const bf16_8*)&kc[srow * STR + ((quad ^ x) << 3)];
            bf16_8 kf1 = *(const bf16_8*)&kc[srow * STR + (((4 | quad) ^ x) << 3)];
            floatx4 a0 = (floatx4){0.f, 0.f, 0.f, 0.f};
            floatx4 a1 = (floatx4){0.f, 0.f, 0.f, 0.f};
            a0 = __builtin_amdgcn_mfma_f32_16x16x32_bf16(kf0, qf[0][0], a0, 0, 0, 0);
            a0 = __builtin_amdgcn_mfma_f32_16x16x32_bf16(kf1, qf[0][1], a0, 0, 0, 0);
            a1 = __builtin_amdgcn_mfma_f32_16x16x32_bf16(kf0, qf[1][0], a1, 0, 0, 0);
            a1 = __builtin_amdgcn_mfma_f32_16x16x32_bf16(kf1, qf[1][1], a1, 0, 0, 0);
            St[0][sb] = a0;
            St[1][sb] = a1;
        }
        // ---- P = exp2(S^T) -> wave-private LDS -> af (this tile) ----
        #pragma unroll
        for (int tt = 0; tt < 2; ++tt) {
            int trow = tt * 16 + i16;
            int xp = (tt + xp0) & 7;
            #pragma unroll
            for (int sb = 0; sb < 4; ++sb) {
                float p0 = EXP2(St[tt][sb][0]);
                float p1 = EXP2(St[tt][sb][1]);
                float p2 = EXP2(St[tt][sb][2]);
                float p3 = EXP2(St[tt][sb][3]);
                l[tt] += (p0 + p1) + (p2 + p3);
                bf16_4 pk;
                pk[0] = (__bf16)p0; pk[1] = (__bf16)p1;
                pk[2] = (__bf16)p2; pk[3] = (__bf16)p3;
                int ch = ((sb << 2) | quad) ^ (xp << 1);
                *(bf16_4*)&pw[trow * STR + (ch << 2)] = pk;
            }
        }
        bf16_8 af[2][2];
        #pragma unroll
        for (int tt = 0; tt < 2; ++tt) {
            int trow = tt * 16 + i16;
            int xp = (tt + xp0) & 7;
            #pragma unroll
            for (int kk = 0; kk < 2; ++kk)
                af[tt][kk] = *(const bf16_8*)&pw[trow * STR + ((((kk << 2) | quad) ^ xp) << 3)];
        }

        // ---- PV_{is-1}: independent of QK_is/softmax_is -> fills latency ----
        if (is > 0) {
            const __bf16* vp = (vprev == 0) ? v0 : ((vprev == 1) ? v1 : v2);
            #pragma unroll
            for (int cn = 0; cn < 4; ++cn) {
                int crow = cn * 16 + i16;
                int xc = (cn + (i16 >> 1)) & 7;       // kap(crow)
                #pragma unroll
                for (int kk = 0; kk < 2; ++kk) {
                    bf16_8 vf = *(const bf16_8*)&vp[crow * STR + ((((kk << 2) | quad) ^ xc) << 3)];
                    O[0][cn] = __builtin_amdgcn_mfma_f32_16x16x32_bf16(vf, afp[0][kk], O[0][cn], 0, 0, 0);
                    O[1][cn] = __builtin_amdgcn_mfma_f32_16x16x32_bf16(vf, afp[1][kk], O[1][cn], 0, 0, 0);
                }
            }
        }
        #pragma unroll
        for (int tt = 0; tt < 2; ++tt)
            #pragma unroll
            for (int kk = 0; kk < 2; ++kk)
                afp[tt][kk] = af[tt][kk];

        // ---- staging of tile is+1 (K -> (is+1)&1, V -> vnext) ----
        if (is < NSTEPS - 1) {
            __bf16* kn = (is & 1) ? k0 : k1;
            __bf16* vn = (vnext == 0) ? v0 : ((vnext == 1) ? v1 : v2);
            #pragma unroll
            for (int rr = 0; rr < 4; ++rr) {
                int srow = si * 4 + rr;
                bf16_4 w;
                w[0] = (__bf16)((const float*)&kr[0])[rr];
                w[1] = (__bf16)((const float*)&kr[1])[rr];
                w[2] = (__bf16)((const float*)&kr[2])[rr];
                w[3] = (__bf16)((const float*)&kr[3])[rr];
                *(bf16_4*)&kn[srow * STR + ((sG ^ (kap(srow) << 1)) << 2)] = w;
            }
            #pragma unroll
            for (int jj = 0; jj < 4; ++jj) {
                int c = c0 + jj;
                bf16_4 w;
                w[0] = (__bf16)vr[jj].x; w[1] = (__bf16)vr[jj].y;
                w[2] = (__bf16)vr[jj].z; w[3] = (__bf16)vr[jj].w;
                *(bf16_4*)&vn[c * STR + ((si ^ (kap(c) << 1)) << 2)] = w;
            }
            __syncthreads();             // publish is+1, retire reads of K_is / V_{is-1}
        }
        // rotate V buffers
        vprev = vcur; vcur = vnext; vnext = (vnext == 2) ? 0 : vnext + 1;
    }

    // ---- final PV for tile 15 (V buffer = 15 % 3 = 0 rotation -> vprev) ----
    {
        const __bf16* vp = (vprev == 0) ? v0 : ((vprev == 1) ? v1 : v2);
        #pragma unroll
        for (int cn = 0; cn < 4; ++cn) {
            int crow = cn * 16 + i16;
            int xc = (cn + (i16 >> 1)) & 7;
            #pragma unroll
            for (int kk = 0; kk < 2; ++kk) {
                bf16_8 vf = *(const bf16_8*)&vp[crow * STR + ((((kk << 2) | quad) ^ xc) << 3)];
                O[0][cn] = __builtin_amdgcn_mfma_f32_16x16x32_bf16(vf, afp[0][kk], O[0][cn], 0, 0, 0);
                O[1][cn] = __builtin_amdgcn_mfma_f32_16x16x32_bf16(vf, afp[1][kk], O[1][cn], 0, 0, 0);
            }
        }
    }

    // ---- denominators (sum 4 quads of column t) + direct O^T stores ----
    float* og = out + (size_t)bh * 65536 + t0 + wave * 32;
    #pragma unroll
    for (int tt = 0; tt < 2; ++tt) {
        float s = l[tt];
        s += __shfl_xor(s, 16);
        s += __shfl_xor(s, 32);
        const float linv = 1.0f / s;
        #pragma unroll
        for (int cn = 0; cn < 4; ++cn)
            #pragma unroll
            for (int r = 0; r < 4; ++r)
                og[(cn * 16 + 4 * quad + r) * 1024 + tt * 16 + i16] = O[tt][cn][r] * linv;
    }
}

extern "C" void kernel_launch(void* const* d_in, const int* in_sizes, int n_in,
                              void* d_out, int out_size, void* d_ws, size_t ws_size,
                              hipStream_t stream) {
    const float* qkv = (const float*)d_in[0];
    float* out = (float*)d_out;
    attn_kernel<<<dim3(512), dim3(NTHREADS), 0, stream>>>(qkv, out);
}